// Round 4
// baseline (265.383 us; speedup 1.0000x reference)
//
#include <hip/hip_runtime.h>
#include <hip/hip_fp16.h>
#include <climits>

// Radon forward projection (parallel beam), 512x512 image, 512 angles,
// 736 detectors x 736 samples, bilinear interpolation.
// Outputs (flat, concatenated): sino [1,512,736] then reco [1,512,512].
//
// R4: shear-mapped lanes. Wave = 64 consecutive detectors; lane l gets a
//     fixed k-offset o(l) = round(-l*dS/sl) so that at uniform loop step j
//     all 64 lanes' slow coords agree to +-0.5 px -> wave footprint is
//     2-3 image rows (~4-9 cache lines per 64 samples, vs ~20-30 for the
//     R3 8x8 tile). Exact per-lane k coverage, per-lane accumulator, no
//     reduction. Pair-packed zero-padded half2 image (P) + transposed (PT),
//     built in ONE prep kernel directly from x+reco.

namespace {
constexpr int H = 512, W = 512, NA = 512, ND = 736, NS = 736;
constexpr int SINO_SIZE = NA * ND;
constexpr int IMG_SIZE = H * W;
constexpr int PW = 516;            // padded pair-row stride (half2 units)
constexpr int PH = 514;            // padded rows
constexpr int PAIR_SIZE = PH * PW; // half2 elements per orientation
}

// ---------- prep: pair-packed padded layouts + reco pass-through -----------
// P [ri][ci] = ( v(ri-1, ci-1), v(ri-1, ci) ), zero outside [0,512)^2
// PT[ri][ci] = ( v(ci-1, ri-1), v(ci,  ri-1) )  (transposed image)
__global__ __launch_bounds__(256) void prep_all(const float* __restrict__ x,
                                                const float* __restrict__ reco,
                                                __half2* __restrict__ P,
                                                __half2* __restrict__ PT,
                                                float* __restrict__ reco_out) {
    const int ci = blockIdx.x * 256 + threadIdx.x;
    const int ri = blockIdx.y;
    if (ci < PW) {
        const int r = ri - 1, c0 = ci - 1, c1 = ci;
        const bool rok  = (unsigned)r  < 512u;
        const bool c0ok = (unsigned)c0 < 512u;
        const bool c1ok = (unsigned)c1 < 512u;
        float v0 = 0.f, v1 = 0.f, w0 = 0.f, w1 = 0.f;
        if (rok && c0ok) { const int i = r * W + c0; v0 = x[i] + reco[i];
                           const int j = c0 * W + r; w0 = x[j] + reco[j]; }
        if (rok && c1ok) { const int i = r * W + c1; v1 = x[i] + reco[i];
                           const int j = c1 * W + r; w1 = x[j] + reco[j]; }
        P [ri * PW + ci] = __floats2half2_rn(v0, v1);
        PT[ri * PW + ci] = __floats2half2_rn(w0, w1);
    }
    if (ri < H && ci < W) {
        const int i = ri * W + ci;
        reco_out[i] = reco[i];
    }
}

// Per-dim k-range for p0 + k*inc in [lo, hi].
__device__ inline void range1(float p0, float inc, float lo, float hi,
                              float& klo, float& khi) {
    if (inc > 1e-6f)       { klo = (lo - p0) / inc; khi = (hi - p0) / inc; }
    else if (inc < -1e-6f) { klo = (hi - p0) / inc; khi = (lo - p0) / inc; }
    else if (p0 >= lo && p0 <= hi) { klo = -1e9f; khi = 1e9f; }
    else                   { klo = 1e9f;  khi = -1e9f; }
}

// Wave = 64 consecutive detectors; per-lane shear offset in k.
// Block 256 = 4 waves = 256 detectors. Grid (3, 512).
__global__ __launch_bounds__(256) void proj_shear(const __half2* __restrict__ P,
                                                  const __half2* __restrict__ PT,
                                                  const float* __restrict__ angles,
                                                  float* __restrict__ sino) {
    const int lane = threadIdx.x & 63;
    const int d = blockIdx.x * 256 + (threadIdx.x >> 6) * 64 + lane;
    const int a = blockIdx.y;

    float si, co;
    sincosf(angles[a], &si, &co);

    const float cx = (W - 1) * 0.5f, cy = (H - 1) * 0.5f;
    const float s  = (float)d - (ND - 1) * 0.5f;
    const float bx = fmaf(s, co, cx);    // px = bx - t*si
    const float by = fmaf(s, si, cy);    // py = by + t*c

    // Orientation: slow dim = row dim of chosen layout; |sl| >= 0.707.
    const __half2* base;
    float f0, fi, s0, sl, dS;
    if (fabsf(co) >= fabsf(si)) { base = P;  f0 = bx; fi = -si; s0 = by; sl = co;  dS = si; }
    else                        { base = PT; f0 = by; fi = co;  s0 = bx; sl = -si; dS = co; }

    const float t0 = -(float)(NS - 1) * 0.5f;
    float F0 = fmaf(t0, fi, f0);
    float S0 = fmaf(t0, sl, s0);
    // Make slow step positive (reverse k traversal; sum order only).
    if (sl < 0.f) {
        F0 = fmaf((float)(NS - 1), fi, F0); fi = -fi;
        S0 = fmaf((float)(NS - 1), sl, S0); sl = -sl;
    }

    // Valid k range: both coords within padded-covered (-1, 512).
    float kloF, khiF, kloS, khiS;
    range1(F0, fi, -0.998f, 511.998f, kloF, khiF);
    range1(S0, sl, -0.998f, 511.998f, kloS, khiS);
    const int kA = max(0,      (int)ceilf(fmaxf(kloF, kloS)));
    const int kB = min(NS - 1, (int)floorf(fminf(khiF, khiS)));

    // Shear offset: slow(lane, j) ~ const across lanes at fixed j.
    const int o = (int)rintf(-(float)lane * dS / sl);
    int jA, jB;
    if (kA <= kB) { jA = kA - o; jB = kB - o; }
    else          { jA = INT_MAX; jB = INT_MIN; }

    // Wave min/max of the j window.
    int Jlo = jA, Jhi = jB;
    #pragma unroll
    for (int off = 1; off < 64; off <<= 1) {
        Jlo = min(Jlo, __shfl_xor(Jlo, off));
        Jhi = max(Jhi, __shfl_xor(Jhi, off));
    }

    float acc = 0.f;
    #pragma unroll 4
    for (int j = Jlo; j <= Jhi; ++j) {
        const int k = j + o;
        if (k >= kA && k <= kB) {
            const float kf = (float)k;
            const float pf = fmaf(kf, fi, F0);
            const float ps = fmaf(kf, sl, S0);
            const float ff = floorf(pf), sf = floorf(ps);
            const float fx = pf - ff,   fy = ps - sf;
            const int idx = ((int)sf + 1) * PW + ((int)ff + 1);
            const float2 A = __half22float2(base[idx]);        // v00, v01
            const float2 B = __half22float2(base[idx + PW]);   // v10, v11
            const float top = fmaf(fx, A.y - A.x, A.x);
            const float bot = fmaf(fx, B.y - B.x, B.x);
            acc += fmaf(fy, bot - top, top);
        }
    }
    if (d < ND) sino[a * ND + d] = acc;   // STEP = 1.0
}

// ---------------- fallback (tiny ws): fused fp32, no staging ----------------
__global__ __launch_bounds__(256) void proj_fused(const float* __restrict__ A,
                                                  const float* __restrict__ B,
                                                  const float* __restrict__ angles,
                                                  float* __restrict__ sino) {
    const int d = blockIdx.x * blockDim.x + threadIdx.x;
    const int a = blockIdx.y;
    if (d >= ND) return;
    float si, c;
    sincosf(angles[a], &si, &c);
    const float cx = (W - 1) * 0.5f, cy = (H - 1) * 0.5f;
    const float s  = (float)d - (ND - 1) * 0.5f;
    const float bx = fmaf(s, c, cx), by = fmaf(s, si, cy);
    const float t0 = -(float)(NS - 1) * 0.5f;
    float acc = 0.f;
    for (int k = 0; k < NS; ++k) {
        const float t = t0 + (float)k;
        const float px = fmaf(t, -si, bx), py = fmaf(t, c, by);
        const float x0f = floorf(px), y0f = floorf(py);
        const float fx = px - x0f, fy = py - y0f;
        const int ix = (int)x0f, iy = (int)y0f;
        auto tap = [&](int yi, int xi) -> float {
            if (xi < 0 || xi >= W || yi < 0 || yi >= H) return 0.f;
            return A[yi * W + xi] + B[yi * W + xi];
        };
        float v = 0.f;
        if (ix >= -1 && iy >= -1 && ix <= W - 1 && iy <= H - 1) {
            const float v00 = tap(iy, ix),     v01 = tap(iy, ix + 1);
            const float v10 = tap(iy + 1, ix), v11 = tap(iy + 1, ix + 1);
            const float top = fmaf(fx, v01 - v00, v00);
            const float bot = fmaf(fx, v11 - v10, v10);
            v = fmaf(fy, bot - top, top);
        }
        acc += v;
    }
    sino[a * ND + d] = acc;
}

__global__ void prep_copy(const float* __restrict__ reco, float* __restrict__ reco_out) {
    int i = blockIdx.x * blockDim.x + threadIdx.x;
    if (i < IMG_SIZE) reco_out[i] = reco[i];
}

extern "C" void kernel_launch(void* const* d_in, const int* in_sizes, int n_in,
                              void* d_out, int out_size, void* d_ws, size_t ws_size,
                              hipStream_t stream) {
    const float* x      = (const float*)d_in[0];
    const float* reco   = (const float*)d_in[1];
    const float* angles = (const float*)d_in[2];
    float* sino     = (float*)d_out;
    float* reco_out = sino + SINO_SIZE;

    const size_t need_pairs = 2 * (size_t)PAIR_SIZE * sizeof(__half2);  // ~2.12 MiB

    if (ws_size >= need_pairs) {
        __half2* P  = (__half2*)d_ws;
        __half2* PT = P + PAIR_SIZE;
        prep_all<<<dim3((PW + 255) / 256, PH), dim3(256), 0, stream>>>(x, reco, P, PT, reco_out);
        proj_shear<<<dim3((ND + 255) / 256, NA), dim3(256), 0, stream>>>(P, PT, angles, sino);
    } else {
        prep_copy<<<dim3((IMG_SIZE + 255) / 256), dim3(256), 0, stream>>>(reco, reco_out);
        proj_fused<<<dim3((ND + 255) / 256, NA), dim3(256), 0, stream>>>(x, reco, angles, sino);
    }
}

// Round 6
// 173.731 us; speedup vs baseline: 1.5276x; 1.5276x over previous
//
#include <hip/hip_runtime.h>
#include <hip/hip_fp16.h>
#include <climits>

// Radon forward projection (parallel beam), 512x512 image, 512 angles,
// 736 detectors x 736 samples, bilinear interpolation.
// Outputs (flat, concatenated): sino [1,512,736] then reco [1,512,512].
//
// R6 (= R5 with type fix): quad-packed fp16 image (whole 2x2 footprint in one
//     8B load), zero-pad ring + clamp (branch-free loop), fp32-computed
//     bilinear weights packed via cvt_pkrtz + v_dot2_f32_f16 accumulate,
//     shear-mapped lanes, LDS-tiled coalesced prep, 128-thread blocks.

namespace {
constexpr int H = 512, W = 512, NA = 512, ND = 736, NS = 736;
constexpr int SINO_SIZE = NA * ND;
constexpr int IMG_SIZE = H * W;
// Quad array: index (ri, ci) covers v rows ri-1..ri, cols ci-1..ci.
// Clamped coords in [-1,512] -> ri,ci in [0,513] -> 514x514, stride 520.
constexpr int QN = 514;
constexpr int QS = 520;                 // row stride in quads (8 B each)
constexpr int QUAD_SIZE = QN * QS;      // quads per orientation
// Pair fallback layout (R4)
constexpr int PW = 516, PH = 514;
constexpr int PAIR_SIZE = PH * PW;
}

typedef __fp16 h2 __attribute__((ext_vector_type(2)));  // matches cvt_pkrtz/fdot2

// ---------- prep: quad layouts (both orientations) + reco pass-through -----
// One block = 32x32 image tile (+1 halo each side). Coalesced global reads;
// transpose via LDS. Also writes the zero pad ring (ws is poisoned!).
__global__ __launch_bounds__(1024) void prep_quads(const float* __restrict__ x,
                                                   const float* __restrict__ reco,
                                                   uint2* __restrict__ Q,
                                                   uint2* __restrict__ QT,
                                                   float* __restrict__ reco_out) {
    __shared__ float tile[34][35];
    const int tx = threadIdx.x, ty = threadIdx.y;      // 32x32
    const int r0 = blockIdx.y * 32, c0 = blockIdx.x * 32;

    // Load 34x34 halo tile: cell (yy,xx) = v(r0-1+yy, c0-1+xx), 0 outside.
    for (int li = ty * 32 + tx; li < 34 * 34; li += 1024) {
        const int yy = li / 34, xx = li - yy * 34;
        const int r = r0 - 1 + yy, c = c0 - 1 + xx;
        float v = 0.f;
        if ((unsigned)r < 512u && (unsigned)c < 512u) {
            const int i = r * W + c;
            v = x[i] + reco[i];
        }
        tile[yy][xx] = v;
    }
    __syncthreads();

    // Quad at (ri,ci): (v(ri-1,ci-1), v(ri-1,ci), v(ri,ci-1), v(ri,ci))
    const int ri = r0 + ty, ci = c0 + tx;
    if (ri < QN && ci < QN) {
        uint2 q;
        q.x = __builtin_bit_cast(unsigned int,
              __builtin_amdgcn_cvt_pkrtz(tile[ty][tx],     tile[ty][tx + 1]));
        q.y = __builtin_bit_cast(unsigned int,
              __builtin_amdgcn_cvt_pkrtz(tile[ty + 1][tx], tile[ty + 1][tx + 1]));
        Q[ri * QS + ci] = q;
    }
    // Transposed-image quad, written at transposed block location (coalesced).
    const int ri2 = c0 + ty, ci2 = r0 + tx;
    if (ri2 < QN && ci2 < QN) {
        uint2 q;
        q.x = __builtin_bit_cast(unsigned int,
              __builtin_amdgcn_cvt_pkrtz(tile[tx][ty],     tile[tx + 1][ty]));
        q.y = __builtin_bit_cast(unsigned int,
              __builtin_amdgcn_cvt_pkrtz(tile[tx][ty + 1], tile[tx + 1][ty + 1]));
        QT[ri2 * QS + ci2] = q;
    }
    // reco pass-through (coalesced)
    const int r = r0 + ty, c = c0 + tx;
    if (r < H && c < W) reco_out[r * W + c] = reco[r * W + c];
}

// Per-dim k-range for p0 + k*inc in [lo, hi].
__device__ inline void range1(float p0, float inc, float lo, float hi,
                              float& klo, float& khi) {
    if (inc > 1e-6f)       { klo = (lo - p0) / inc; khi = (hi - p0) / inc; }
    else if (inc < -1e-6f) { klo = (hi - p0) / inc; khi = (lo - p0) / inc; }
    else if (p0 >= lo && p0 <= hi) { klo = -1e9f; khi = 1e9f; }
    else                   { klo = 1e9f;  khi = -1e9f; }
}

// Wave = 64 consecutive detectors with per-lane shear k-offset.
// Block 128 = 2 waves. Grid (6, 512).
__global__ __launch_bounds__(128) void proj_quad(const uint2* __restrict__ Q,
                                                 const uint2* __restrict__ QT,
                                                 const float* __restrict__ angles,
                                                 float* __restrict__ sino) {
    const int lane = threadIdx.x & 63;
    const int d = blockIdx.x * 128 + (threadIdx.x >> 6) * 64 + lane;
    const int a = blockIdx.y;

    float si, co;
    sincosf(angles[a], &si, &co);

    const float cx = (W - 1) * 0.5f, cy = (H - 1) * 0.5f;
    const float s  = (float)d - (ND - 1) * 0.5f;
    const float bx = fmaf(s, co, cx);    // px = bx - t*si
    const float by = fmaf(s, si, cy);    // py = by + t*c

    // Orientation: slow dim = row dim of chosen layout; |sl| >= 0.707.
    const uint2* base;
    float f0, fi, s0, sl, dS;
    if (fabsf(co) >= fabsf(si)) { base = Q;  f0 = bx; fi = -si; s0 = by; sl = co;  dS = si; }
    else                        { base = QT; f0 = by; fi = co;  s0 = bx; sl = -si; dS = co; }

    const float t0 = -(float)(NS - 1) * 0.5f;
    float F0 = fmaf(t0, fi, f0);
    float S0 = fmaf(t0, sl, s0);
    if (sl < 0.f) {   // make slow step positive (reverses sum order only)
        F0 = fmaf((float)(NS - 1), fi, F0); fi = -fi;
        S0 = fmaf((float)(NS - 1), sl, S0); sl = -sl;
    }

    // Valid k range (conservative; clamp handles the rest).
    float kloF, khiF, kloS, khiS;
    range1(F0, fi, -0.999f, 511.999f, kloF, khiF);
    range1(S0, sl, -0.999f, 511.999f, kloS, khiS);
    const int kA = max(0,      (int)ceilf(fmaxf(kloF, kloS)));
    const int kB = min(NS - 1, (int)floorf(fminf(khiF, khiS)));

    // Shear offset: aligns slow coords across lanes at fixed loop index j.
    const int o = (int)rintf(-(float)lane * dS / sl);
    const float F0l = fmaf((float)o, fi, F0);
    const float S0l = fmaf((float)o, sl, S0);

    int jA, jB;
    if (kA <= kB) { jA = kA - o; jB = kB - o; }
    else          { jA = INT_MAX; jB = INT_MIN; }
    int Jlo = jA, Jhi = jB;
    #pragma unroll
    for (int off = 1; off < 64; off <<= 1) {
        Jlo = min(Jlo, __shfl_xor(Jlo, off));
        Jhi = max(Jhi, __shfl_xor(Jhi, off));
    }

    float acc = 0.f;
    #pragma unroll 4
    for (int j = Jlo; j <= Jhi; ++j) {
        const float jf = (float)j;
        float pf = fmaf(jf, fi, F0l);
        float ps = fmaf(jf, sl, S0l);
        // Clamp into the zero-pad ring: out-of-window samples contribute 0.
        pf = fminf(fmaxf(pf, -1.f), 512.f);   // v_med3_f32
        ps = fminf(fmaxf(ps, -1.f), 512.f);
        const float ff = floorf(pf), sf = floorf(ps);
        const float fx = pf - ff,   fy = ps - sf;
        const int idx = ((int)sf + 1) * QS + ((int)ff + 1);
        const uint2 q = base[idx];
        const h2 top = __builtin_bit_cast(h2, q.x);   // v00, v01
        const h2 bot = __builtin_bit_cast(h2, q.y);   // v10, v11
        const float gx = 1.f - fx, gy = 1.f - fy;
        const h2 w0 = __builtin_amdgcn_cvt_pkrtz(gx * gy, fx * gy);
        const h2 w1 = __builtin_amdgcn_cvt_pkrtz(gx * fy, fx * fy);
#if __has_builtin(__builtin_amdgcn_fdot2)
        acc = __builtin_amdgcn_fdot2(w0, top, acc, false);
        acc = __builtin_amdgcn_fdot2(w1, bot, acc, false);
#else
        acc += (float)w0.x * (float)top.x + (float)w0.y * (float)top.y;
        acc += (float)w1.x * (float)bot.x + (float)w1.y * (float)bot.y;
#endif
    }
    if (d < ND) sino[a * ND + d] = acc;   // STEP = 1.0
}

// ================= tier-2 fallback: R4 pair layout =========================
__global__ __launch_bounds__(256) void prep_all(const float* __restrict__ x,
                                                const float* __restrict__ reco,
                                                __half2* __restrict__ P,
                                                __half2* __restrict__ PT,
                                                float* __restrict__ reco_out) {
    const int ci = blockIdx.x * 256 + threadIdx.x;
    const int ri = blockIdx.y;
    if (ci < PW) {
        const int r = ri - 1, c0 = ci - 1, c1 = ci;
        const bool rok  = (unsigned)r  < 512u;
        const bool c0ok = (unsigned)c0 < 512u;
        const bool c1ok = (unsigned)c1 < 512u;
        float v0 = 0.f, v1 = 0.f, w0 = 0.f, w1 = 0.f;
        if (rok && c0ok) { const int i = r * W + c0; v0 = x[i] + reco[i];
                           const int j = c0 * W + r; w0 = x[j] + reco[j]; }
        if (rok && c1ok) { const int i = r * W + c1; v1 = x[i] + reco[i];
                           const int j = c1 * W + r; w1 = x[j] + reco[j]; }
        P [ri * PW + ci] = __floats2half2_rn(v0, v1);
        PT[ri * PW + ci] = __floats2half2_rn(w0, w1);
    }
    if (ri < H && ci < W) reco_out[ri * W + ci] = reco[ri * W + ci];
}

__global__ __launch_bounds__(256) void proj_shear(const __half2* __restrict__ P,
                                                  const __half2* __restrict__ PT,
                                                  const float* __restrict__ angles,
                                                  float* __restrict__ sino) {
    const int lane = threadIdx.x & 63;
    const int d = blockIdx.x * 256 + (threadIdx.x >> 6) * 64 + lane;
    const int a = blockIdx.y;
    float si, co;
    sincosf(angles[a], &si, &co);
    const float cx = (W - 1) * 0.5f, cy = (H - 1) * 0.5f;
    const float s  = (float)d - (ND - 1) * 0.5f;
    const float bx = fmaf(s, co, cx), by = fmaf(s, si, cy);
    const __half2* base;
    float f0, fi, s0, sl, dS;
    if (fabsf(co) >= fabsf(si)) { base = P;  f0 = bx; fi = -si; s0 = by; sl = co;  dS = si; }
    else                        { base = PT; f0 = by; fi = co;  s0 = bx; sl = -si; dS = co; }
    const float t0 = -(float)(NS - 1) * 0.5f;
    float F0 = fmaf(t0, fi, f0);
    float S0 = fmaf(t0, sl, s0);
    if (sl < 0.f) {
        F0 = fmaf((float)(NS - 1), fi, F0); fi = -fi;
        S0 = fmaf((float)(NS - 1), sl, S0); sl = -sl;
    }
    float kloF, khiF, kloS, khiS;
    range1(F0, fi, -0.998f, 511.998f, kloF, khiF);
    range1(S0, sl, -0.998f, 511.998f, kloS, khiS);
    const int kA = max(0,      (int)ceilf(fmaxf(kloF, kloS)));
    const int kB = min(NS - 1, (int)floorf(fminf(khiF, khiS)));
    const int o = (int)rintf(-(float)lane * dS / sl);
    int jA, jB;
    if (kA <= kB) { jA = kA - o; jB = kB - o; }
    else          { jA = INT_MAX; jB = INT_MIN; }
    int Jlo = jA, Jhi = jB;
    #pragma unroll
    for (int off = 1; off < 64; off <<= 1) {
        Jlo = min(Jlo, __shfl_xor(Jlo, off));
        Jhi = max(Jhi, __shfl_xor(Jhi, off));
    }
    float acc = 0.f;
    #pragma unroll 4
    for (int j = Jlo; j <= Jhi; ++j) {
        const int k = j + o;
        if (k >= kA && k <= kB) {
            const float kf = (float)k;
            const float pf = fmaf(kf, fi, F0);
            const float ps = fmaf(kf, sl, S0);
            const float ff = floorf(pf), sf = floorf(ps);
            const float fx = pf - ff,   fy = ps - sf;
            const int idx = ((int)sf + 1) * PW + ((int)ff + 1);
            const float2 A = __half22float2(base[idx]);
            const float2 B = __half22float2(base[idx + PW]);
            const float top = fmaf(fx, A.y - A.x, A.x);
            const float bot = fmaf(fx, B.y - B.x, B.x);
            acc += fmaf(fy, bot - top, top);
        }
    }
    if (d < ND) sino[a * ND + d] = acc;
}

// ================= tier-3 fallback: fused fp32 =============================
__global__ __launch_bounds__(256) void proj_fused(const float* __restrict__ A,
                                                  const float* __restrict__ B,
                                                  const float* __restrict__ angles,
                                                  float* __restrict__ sino) {
    const int d = blockIdx.x * blockDim.x + threadIdx.x;
    const int a = blockIdx.y;
    if (d >= ND) return;
    float si, c;
    sincosf(angles[a], &si, &c);
    const float cx = (W - 1) * 0.5f, cy = (H - 1) * 0.5f;
    const float s  = (float)d - (ND - 1) * 0.5f;
    const float bx = fmaf(s, c, cx), by = fmaf(s, si, cy);
    const float t0 = -(float)(NS - 1) * 0.5f;
    float acc = 0.f;
    for (int k = 0; k < NS; ++k) {
        const float t = t0 + (float)k;
        const float px = fmaf(t, -si, bx), py = fmaf(t, c, by);
        const float x0f = floorf(px), y0f = floorf(py);
        const float fx = px - x0f, fy = py - y0f;
        const int ix = (int)x0f, iy = (int)y0f;
        auto tap = [&](int yi, int xi) -> float {
            if (xi < 0 || xi >= W || yi < 0 || yi >= H) return 0.f;
            return A[yi * W + xi] + B[yi * W + xi];
        };
        float v = 0.f;
        if (ix >= -1 && iy >= -1 && ix <= W - 1 && iy <= H - 1) {
            const float v00 = tap(iy, ix),     v01 = tap(iy, ix + 1);
            const float v10 = tap(iy + 1, ix), v11 = tap(iy + 1, ix + 1);
            const float top = fmaf(fx, v01 - v00, v00);
            const float bot = fmaf(fx, v11 - v10, v10);
            v = fmaf(fy, bot - top, top);
        }
        acc += v;
    }
    sino[a * ND + d] = acc;
}

__global__ void prep_copy(const float* __restrict__ reco, float* __restrict__ reco_out) {
    int i = blockIdx.x * blockDim.x + threadIdx.x;
    if (i < IMG_SIZE) reco_out[i] = reco[i];
}

extern "C" void kernel_launch(void* const* d_in, const int* in_sizes, int n_in,
                              void* d_out, int out_size, void* d_ws, size_t ws_size,
                              hipStream_t stream) {
    const float* x      = (const float*)d_in[0];
    const float* reco   = (const float*)d_in[1];
    const float* angles = (const float*)d_in[2];
    float* sino     = (float*)d_out;
    float* reco_out = sino + SINO_SIZE;

    const size_t need_quads = 2 * (size_t)QUAD_SIZE * sizeof(uint2);    // ~4.28 MiB
    const size_t need_pairs = 2 * (size_t)PAIR_SIZE * sizeof(__half2);  // ~2.12 MiB

    if (ws_size >= need_quads) {
        uint2* Q  = (uint2*)d_ws;
        uint2* QT = Q + QUAD_SIZE;
        prep_quads<<<dim3(17, 17), dim3(32, 32), 0, stream>>>(x, reco, Q, QT, reco_out);
        proj_quad<<<dim3(6, NA), dim3(128), 0, stream>>>(Q, QT, angles, sino);
    } else if (ws_size >= need_pairs) {
        __half2* P  = (__half2*)d_ws;
        __half2* PT = P + PAIR_SIZE;
        prep_all<<<dim3((PW + 255) / 256, PH), dim3(256), 0, stream>>>(x, reco, P, PT, reco_out);
        proj_shear<<<dim3((ND + 255) / 256, NA), dim3(256), 0, stream>>>(P, PT, angles, sino);
    } else {
        prep_copy<<<dim3((IMG_SIZE + 255) / 256), dim3(256), 0, stream>>>(reco, reco_out);
        proj_fused<<<dim3((ND + 255) / 256, NA), dim3(256), 0, stream>>>(x, reco, angles, sino);
    }
}

// Round 7
// 153.440 us; speedup vs baseline: 1.7296x; 1.1322x over previous
//
#include <hip/hip_runtime.h>
#include <hip/hip_fp16.h>
#include <climits>

// Radon forward projection (parallel beam), 512x512 image, 512 angles,
// 736 detectors x 736 samples, bilinear interpolation.
// Outputs (flat, concatenated): sino [1,512,736] then reco [1,512,512].
//
// R7: load-balance via 4-way k-range split (blockIdx.z) + relaxed fp32
//     atomics (max wave length 730 -> ~183 iters; occupancy was 36% from
//     longest-wave drain), column-pair quads (interp = pk_sub + pk_fma +
//     fdot2), address via exact fp32 fma, sino zeroing folded into prep.

namespace {
constexpr int H = 512, W = 512, NA = 512, ND = 736, NS = 736;
constexpr int SINO_SIZE = NA * ND;
constexpr int IMG_SIZE = H * W;
// Quad array: entry (ri,ci), ri,ci in [0,513]:
//   q.x = (v(ri-1,ci-1), v(ri,ci-1))   column pair at ci-1
//   q.y = (v(ri-1,ci),   v(ri,ci))     column pair at ci
// zero outside [0,512)^2. Shifted sample (sf',ff') = (iy+1, ix+1).
constexpr int QN = 514;
constexpr int QS = 520;                 // row stride in quads (8 B each)
constexpr int QUAD_SIZE = QN * QS;
constexpr int KSPLIT = 4;
}

typedef __fp16 h2 __attribute__((ext_vector_type(2)));

// ---------- prep: quad layouts (both orientations) + reco + sino zero ------
__global__ __launch_bounds__(1024) void prep_quads(const float* __restrict__ x,
                                                   const float* __restrict__ reco,
                                                   uint2* __restrict__ Q,
                                                   uint2* __restrict__ QT,
                                                   float* __restrict__ reco_out,
                                                   float* __restrict__ sino) {
    __shared__ float tile[34][35];
    const int tx = threadIdx.x, ty = threadIdx.y;      // 32x32
    const int r0 = blockIdx.y * 32, c0 = blockIdx.x * 32;

    // Zero the sinogram (atomically accumulated later; d_out is poisoned).
    const int nthr = gridDim.x * gridDim.y * 1024;
    const int gtid = (blockIdx.y * gridDim.x + blockIdx.x) * 1024 + ty * 32 + tx;
    for (int i = gtid; i < SINO_SIZE; i += nthr) sino[i] = 0.f;

    // Load 34x34 halo tile: cell (yy,xx) = v(r0-1+yy, c0-1+xx), 0 outside.
    for (int li = ty * 32 + tx; li < 34 * 34; li += 1024) {
        const int yy = li / 34, xx = li - yy * 34;
        const int r = r0 - 1 + yy, c = c0 - 1 + xx;
        float v = 0.f;
        if ((unsigned)r < 512u && (unsigned)c < 512u) {
            const int i = r * W + c;
            v = x[i] + reco[i];
        }
        tile[yy][xx] = v;
    }
    __syncthreads();

    // Q quad (ri,ci): column pairs (see layout comment).
    const int ri = r0 + ty, ci = c0 + tx;
    if (ri < QN && ci < QN) {
        uint2 q;
        q.x = __builtin_bit_cast(unsigned int,
              __builtin_amdgcn_cvt_pkrtz(tile[ty][tx],     tile[ty + 1][tx]));
        q.y = __builtin_bit_cast(unsigned int,
              __builtin_amdgcn_cvt_pkrtz(tile[ty][tx + 1], tile[ty + 1][tx + 1]));
        Q[ri * QS + ci] = q;
    }
    // Transposed-image quad, written at transposed block location.
    const int ri2 = c0 + ty, ci2 = r0 + tx;
    if (ri2 < QN && ci2 < QN) {
        uint2 q;
        q.x = __builtin_bit_cast(unsigned int,
              __builtin_amdgcn_cvt_pkrtz(tile[tx][ty],     tile[tx][ty + 1]));
        q.y = __builtin_bit_cast(unsigned int,
              __builtin_amdgcn_cvt_pkrtz(tile[tx + 1][ty], tile[tx + 1][ty + 1]));
        QT[ri2 * QS + ci2] = q;
    }
    // reco pass-through (coalesced)
    const int r = r0 + ty, c = c0 + tx;
    if (r < H && c < W) reco_out[r * W + c] = reco[r * W + c];
}

// Per-dim k-range for p0 + k*inc in [lo, hi].
__device__ inline void range1(float p0, float inc, float lo, float hi,
                              float& klo, float& khi) {
    if (inc > 1e-6f)       { klo = (lo - p0) / inc; khi = (hi - p0) / inc; }
    else if (inc < -1e-6f) { klo = (hi - p0) / inc; khi = (lo - p0) / inc; }
    else if (p0 >= lo && p0 <= hi) { klo = -1e9f; khi = 1e9f; }
    else                   { klo = 1e9f;  khi = -1e9f; }
}

// Wave = 64 consecutive detectors, shear-mapped k; blockIdx.z = k-quarter.
__global__ __launch_bounds__(128) void proj_quad(const uint2* __restrict__ Q,
                                                 const uint2* __restrict__ QT,
                                                 const float* __restrict__ angles,
                                                 float* __restrict__ sino) {
    const int lane = threadIdx.x & 63;
    const int d = blockIdx.x * 128 + (threadIdx.x >> 6) * 64 + lane;
    const int a = blockIdx.y;
    const int z = blockIdx.z;

    float si, co;
    sincosf(angles[a], &si, &co);

    const float cx = (W - 1) * 0.5f, cy = (H - 1) * 0.5f;
    const float s  = (float)d - (ND - 1) * 0.5f;
    const float bx = fmaf(s, co, cx);    // px = bx - t*si
    const float by = fmaf(s, si, cy);    // py = by + t*c

    // Orientation: slow dim = row dim of chosen layout; |sl| >= 0.707.
    const uint2* base;
    float f0, fi, s0, sl, dS;
    if (fabsf(co) >= fabsf(si)) { base = Q;  f0 = bx; fi = -si; s0 = by; sl = co;  dS = si; }
    else                        { base = QT; f0 = by; fi = co;  s0 = bx; sl = -si; dS = co; }

    const float t0 = -(float)(NS - 1) * 0.5f;
    float F0 = fmaf(t0, fi, f0);
    float S0 = fmaf(t0, sl, s0);
    if (sl < 0.f) {   // make slow step positive (reverses sum order only)
        F0 = fmaf((float)(NS - 1), fi, F0); fi = -fi;
        S0 = fmaf((float)(NS - 1), sl, S0); sl = -sl;
    }

    // Valid k range (conservative; clamp handles out-of-window samples).
    float kloF, khiF, kloS, khiS;
    range1(F0, fi, -0.9999f, 511.9999f, kloF, khiF);
    range1(S0, sl, -0.9999f, 511.9999f, kloS, khiS);
    const int kA = max(0,      (int)ceilf(fmaxf(kloF, kloS)));
    const int kB = min(NS - 1, (int)floorf(fminf(khiF, khiS)));

    // Shear offset: aligns slow coords across lanes at fixed loop index j.
    const int o = (int)rintf(-(float)lane * dS / sl);
    // +1 shift folds the pad-ring offset into the clamp domain [0, 513].
    const float F1 = fmaf((float)o, fi, F0) + 1.f;
    const float S1 = fmaf((float)o, sl, S0) + 1.f;

    int jA, jB;
    if (kA <= kB) { jA = kA - o; jB = kB - o; }
    else          { jA = INT_MAX; jB = INT_MIN; }
    int Jlo = jA, Jhi = jB;
    #pragma unroll
    for (int off = 1; off < 64; off <<= 1) {
        Jlo = min(Jlo, __shfl_xor(Jlo, off));
        Jhi = max(Jhi, __shfl_xor(Jhi, off));
    }
    if (Jlo > Jhi) return;                 // whole wave empty
    const int L  = Jhi - Jlo + 1;
    const int js = Jlo + (L * z) / KSPLIT;
    const int je = Jlo + (L * (z + 1)) / KSPLIT - 1;

    float acc = 0.f;
    float jf = (float)js;
    #pragma unroll 4
    for (int j = js; j <= je; ++j) {
        float pf = fmaf(jf, fi, F1);
        float ps = fmaf(jf, sl, S1);
        jf += 1.f;
        pf = fminf(fmaxf(pf, 0.f), 513.f);   // clamp into zero-pad ring
        ps = fminf(fmaxf(ps, 0.f), 513.f);
        const float ff = floorf(pf), sf = floorf(ps);
        const float fx = pf - ff,   fy = ps - sf;
        const int ai = (int)fmaf(sf, 520.f, ff);   // exact (< 2^24)
        const uint2 q = base[ai];
        const h2 l = __builtin_bit_cast(h2, q.x);   // (v00, v10)
        const h2 r = __builtin_bit_cast(h2, q.y);   // (v01, v11)
        const h2 fx2 = __builtin_amdgcn_cvt_pkrtz(fx, fx);
        const h2 m = l + fx2 * (r - l);             // pk_sub + pk_fma
        const h2 wy = __builtin_amdgcn_cvt_pkrtz(1.f - fy, fy);
#if __has_builtin(__builtin_amdgcn_fdot2)
        acc = __builtin_amdgcn_fdot2(wy, m, acc, false);
#else
        acc += (float)wy.x * (float)m.x + (float)wy.y * (float)m.y;
#endif
    }
    if (d < ND)
        __hip_atomic_fetch_add(&sino[a * ND + d], acc,
                               __ATOMIC_RELAXED, __HIP_MEMORY_SCOPE_AGENT);
}

// ================= fallback (tiny ws): fused fp32 ==========================
__global__ __launch_bounds__(256) void proj_fused(const float* __restrict__ A,
                                                  const float* __restrict__ B,
                                                  const float* __restrict__ angles,
                                                  float* __restrict__ sino) {
    const int d = blockIdx.x * blockDim.x + threadIdx.x;
    const int a = blockIdx.y;
    if (d >= ND) return;
    float si, c;
    sincosf(angles[a], &si, &c);
    const float cx = (W - 1) * 0.5f, cy = (H - 1) * 0.5f;
    const float s  = (float)d - (ND - 1) * 0.5f;
    const float bx = fmaf(s, c, cx), by = fmaf(s, si, cy);
    const float t0 = -(float)(NS - 1) * 0.5f;
    float acc = 0.f;
    for (int k = 0; k < NS; ++k) {
        const float t = t0 + (float)k;
        const float px = fmaf(t, -si, bx), py = fmaf(t, c, by);
        const float x0f = floorf(px), y0f = floorf(py);
        const float fx = px - x0f, fy = py - y0f;
        const int ix = (int)x0f, iy = (int)y0f;
        auto tap = [&](int yi, int xi) -> float {
            if (xi < 0 || xi >= W || yi < 0 || yi >= H) return 0.f;
            return A[yi * W + xi] + B[yi * W + xi];
        };
        float v = 0.f;
        if (ix >= -1 && iy >= -1 && ix <= W - 1 && iy <= H - 1) {
            const float v00 = tap(iy, ix),     v01 = tap(iy, ix + 1);
            const float v10 = tap(iy + 1, ix), v11 = tap(iy + 1, ix + 1);
            const float top = fmaf(fx, v01 - v00, v00);
            const float bot = fmaf(fx, v11 - v10, v10);
            v = fmaf(fy, bot - top, top);
        }
        acc += v;
    }
    sino[a * ND + d] = acc;
}

__global__ void prep_copy(const float* __restrict__ reco, float* __restrict__ reco_out) {
    int i = blockIdx.x * blockDim.x + threadIdx.x;
    if (i < IMG_SIZE) reco_out[i] = reco[i];
}

extern "C" void kernel_launch(void* const* d_in, const int* in_sizes, int n_in,
                              void* d_out, int out_size, void* d_ws, size_t ws_size,
                              hipStream_t stream) {
    const float* x      = (const float*)d_in[0];
    const float* reco   = (const float*)d_in[1];
    const float* angles = (const float*)d_in[2];
    float* sino     = (float*)d_out;
    float* reco_out = sino + SINO_SIZE;

    const size_t need_quads = 2 * (size_t)QUAD_SIZE * sizeof(uint2);    // ~4.28 MiB

    if (ws_size >= need_quads) {
        uint2* Q  = (uint2*)d_ws;
        uint2* QT = Q + QUAD_SIZE;
        prep_quads<<<dim3(17, 17), dim3(32, 32), 0, stream>>>(x, reco, Q, QT, reco_out, sino);
        proj_quad<<<dim3(6, NA, KSPLIT), dim3(128), 0, stream>>>(Q, QT, angles, sino);
    } else {
        prep_copy<<<dim3((IMG_SIZE + 255) / 256), dim3(256), 0, stream>>>(reco, reco_out);
        proj_fused<<<dim3((ND + 255) / 256, NA), dim3(256), 0, stream>>>(x, reco, angles, sino);
    }
}